// Round 22
// baseline (404.040 us; speedup 1.0000x reference)
//
#include <hip/hip_runtime.h>
#include <math.h>

#define BB 4
#define TT 2048
#define DD 1024
#define HH 128
#define EPSF 1e-6f
#define BT (BB*TT)   // 8192
#define CC 128       // chunk length
#define NCH (TT/CC)  // 16 chunks per batch
#define NIC (CC/2)   // 64 double-steps per chunk
#define NSCAN (BB*NCH)  // 64 chunk-scan blocks
#define WPAD 140     // gapped row stride: col h stored at h + (h>>5)*4

typedef float f32x2 __attribute__((ext_vector_type(2)));

// gap-insertion column map (reads 2-way bank-aliased = free)
__device__ __forceinline__ int gcol(int h) { return h + ((h >> 5) << 2); }

// 8-lane butterfly sum, pure DPP/VALU (no DS pipe)
__device__ __forceinline__ float red8(float x) {
    x += __int_as_float(__builtin_amdgcn_mov_dpp(__float_as_int(x), 0xB1,  0xF, 0xF, true));
    x += __int_as_float(__builtin_amdgcn_mov_dpp(__float_as_int(x), 0x4E,  0xF, 0xF, true));
    x += __int_as_float(__builtin_amdgcn_mov_dpp(__float_as_int(x), 0x141, 0xF, 0xF, true));
    return x;
}
// 16-lane butterfly sum (adds ROW_MIRROR)
__device__ __forceinline__ float red16(float x) {
    x = red8(x);
    x += __int_as_float(__builtin_amdgcn_mov_dpp(__float_as_int(x), 0x140, 0xF, 0xF, true));
    return x;
}

// ---------------------------------------------------------------------------
// proj3 v24: 128-row tiles, acc2[8][4] packed (4 b128 DS reads per 64 FMA —
// 2x better FMA:DS than v23). Grid (BT/128, 6): which = y>>1 (0=K,1=Q,2=V),
// half = y&1. Writes k-half partials to Pp[(which*2+half)*BT*HH + ...].
// Staging buffers sized for 128 rows: xT[32][132] (writes r<=127, reads
// ty*8..ty*8+8 <= 128 — audited, R20 lesson).
// ---------------------------------------------------------------------------
__global__ __launch_bounds__(256) void proj3_kernel(
    const float* __restrict__ x,
    const float* __restrict__ Wk, const float* __restrict__ Wq,
    const float* __restrict__ Wv, float* __restrict__ Pp)
{
    const int row0  = blockIdx.x * 128;
    const int which = blockIdx.y >> 1;
    const int half  = blockIdx.y & 1;
    const float* W = (which == 0) ? Wk : (which == 1) ? Wq : Wv;

    __shared__ float xT[32][132];
    __shared__ float wT[32][WPAD];

    const int tid = threadIdx.x;
    const int tx = tid & 15;
    const int ty = tid >> 4;       // 0..15, rows ty*8..+8
    const int gx = tx * 8 + ((tx >> 2) << 2);

    f32x2 acc2[8][4];
    #pragma unroll
    for (int i = 0; i < 8; i++)
        #pragma unroll
        for (int jp = 0; jp < 4; jp++) acc2[i][jp] = (f32x2){0.f, 0.f};

    const int kbase = half * (DD / 2);
    for (int k0 = kbase; k0 < kbase + DD / 2; k0 += 32) {
        #pragma unroll
        for (int l = 0; l < 4; l++) {    // xT: 128 rows x 32 k (transposed)
            int f = tid + l * 256;
            int r = f >> 3, cg = f & 7;
            float4 v = *(const float4*)(x + (size_t)(row0 + r) * DD + k0 + cg * 4);
            xT[cg*4+0][r] = v.x; xT[cg*4+1][r] = v.y;
            xT[cg*4+2][r] = v.z; xT[cg*4+3][r] = v.w;
        }
        #pragma unroll
        for (int l = 0; l < 4; l++) {    // wT: 128 h x 32 k (gapped)
            int f = tid + l * 256;
            int h = f >> 3, cg = f & 7;
            int gc = gcol(h);
            float4 v = *(const float4*)(W + (size_t)h * DD + k0 + cg * 4);
            wT[cg*4+0][gc] = v.x; wT[cg*4+1][gc] = v.y;
            wT[cg*4+2][gc] = v.z; wT[cg*4+3][gc] = v.w;
        }
        __syncthreads();
        #pragma unroll
        for (int kk = 0; kk < 32; kk++) {
            float4 x0 = *(const float4*)&xT[kk][ty * 8];
            float4 x1 = *(const float4*)&xT[kk][ty * 8 + 4];
            float4 w0 = *(const float4*)&wT[kk][gx];
            float4 w1 = *(const float4*)&wT[kk][gx + 4];
            f32x2 wa[4] = {{w0.x, w0.y}, {w0.z, w0.w},
                           {w1.x, w1.y}, {w1.z, w1.w}};
            float xa[8] = {x0.x, x0.y, x0.z, x0.w, x1.x, x1.y, x1.z, x1.w};
            #pragma unroll
            for (int i = 0; i < 8; i++) {
                const f32x2 xb = {xa[i], xa[i]};
                #pragma unroll
                for (int jp = 0; jp < 4; jp++)
                    acc2[i][jp] += xb * wa[jp];
            }
        }
        __syncthreads();
    }

    float* Pd = Pp + (size_t)(which * 2 + half) * BT * HH;
    #pragma unroll
    for (int i = 0; i < 8; i++) {
        int row = row0 + ty * 8 + i;
        float4 o0 = {acc2[i][0].x, acc2[i][0].y, acc2[i][1].x, acc2[i][1].y};
        float4 o1 = {acc2[i][2].x, acc2[i][2].y, acc2[i][3].x, acc2[i][3].y};
        *(float4*)(Pd + (size_t)row * HH + tx * 8)     = o0;
        *(float4*)(Pd + (size_t)row * HH + tx * 8 + 4) = o1;
    }
}

// ---------------------------------------------------------------------------
// combine: P = part0 + part1 + bias for K,Q,V; epilogues rn = 1/(||k||+eps)
// and s = q.k. Memory-bound. Grid BT/32, 256 threads. (v23-verified.)
// ---------------------------------------------------------------------------
__global__ __launch_bounds__(256) void combine_kernel(
    const float* __restrict__ Pp,
    const float* __restrict__ bk, const float* __restrict__ bq,
    const float* __restrict__ bv,
    float* __restrict__ K, float* __restrict__ Q, float* __restrict__ V,
    float* __restrict__ rn, float* __restrict__ Sarr)
{
    const int row0 = blockIdx.x * 32;
    const int tid = threadIdx.x;
    const int tx = tid & 15;
    const int ty = tid >> 4;       // rows ty*2..+2

    #pragma unroll
    for (int i = 0; i < 2; i++) {
        const int row = row0 + ty * 2 + i;
        const size_t base = (size_t)row * HH + tx * 8;

        float kv[8], qv[8], vv[8];
        #pragma unroll
        for (int w = 0; w < 3; w++) {
            const float* p0 = Pp + (size_t)(w * 2)     * BT * HH + base;
            const float* p1 = Pp + (size_t)(w * 2 + 1) * BT * HH + base;
            const float* bias = (w == 0) ? bk : (w == 1) ? bq : bv;
            float* dst = (w == 0) ? (kv) : (w == 1) ? (qv) : (vv);
            float4 a0 = *(const float4*)p0;
            float4 a1 = *(const float4*)(p0 + 4);
            float4 c0 = *(const float4*)p1;
            float4 c1 = *(const float4*)(p1 + 4);
            dst[0] = a0.x + c0.x + bias[tx*8+0];
            dst[1] = a0.y + c0.y + bias[tx*8+1];
            dst[2] = a0.z + c0.z + bias[tx*8+2];
            dst[3] = a0.w + c0.w + bias[tx*8+3];
            dst[4] = a1.x + c1.x + bias[tx*8+4];
            dst[5] = a1.y + c1.y + bias[tx*8+5];
            dst[6] = a1.z + c1.z + bias[tx*8+6];
            dst[7] = a1.w + c1.w + bias[tx*8+7];
        }

        float4 k0 = {kv[0], kv[1], kv[2], kv[3]};
        float4 k1 = {kv[4], kv[5], kv[6], kv[7]};
        float4 q0 = {qv[0], qv[1], qv[2], qv[3]};
        float4 q1 = {qv[4], qv[5], qv[6], qv[7]};
        float4 v0 = {vv[0], vv[1], vv[2], vv[3]};
        float4 v1 = {vv[4], vv[5], vv[6], vv[7]};
        *(float4*)(K + base)     = k0;
        *(float4*)(K + base + 4) = k1;
        *(float4*)(Q + base)     = q0;
        *(float4*)(Q + base + 4) = q1;
        *(float4*)(V + base)     = v0;
        *(float4*)(V + base + 4) = v1;

        float p2 = 0.f, pkq = 0.f;
        #pragma unroll
        for (int j = 0; j < 8; j++) {
            p2  += kv[j] * kv[j];
            pkq += qv[j] * kv[j];
        }
        p2  = red16(p2);
        pkq = red16(pkq);
        if (tx == 0) {
            rn[row]   = 1.0f / (sqrtf(p2) + EPSF);
            Sarr[row] = pkq;
        }
    }
}

// ---------------------------------------------------------------------------
// H[b][c] = sum_{t in chunk} (rn k)(rn k)^T. Grid (64, 4), gapped aT.
// ---------------------------------------------------------------------------
__global__ __launch_bounds__(256) void ugram_kernel(
    const float* __restrict__ K, const float* __restrict__ rn,
    float* __restrict__ H)
{
    const int bi = blockIdx.x;
    const int r0 = blockIdx.y * 32;

    const float* Kc = K + (size_t)bi * CC * HH;
    const float* Rc = rn + (size_t)bi * CC;

    __shared__ float vT[32][36];
    __shared__ float aT[32][WPAD];

    const int tid = threadIdx.x;
    const int tx = tid & 15, ty = tid >> 4;
    const int gx = tx * 8 + ((tx >> 2) << 2);

    float acc[2][8];
    #pragma unroll
    for (int i = 0; i < 2; i++)
        #pragma unroll
        for (int j = 0; j < 8; j++) acc[i][j] = 0.f;

    for (int s0 = 0; s0 < CC; s0 += 32) {
        {   int sr = tid >> 3, rc4 = tid & 7;
            float sc = Rc[s0 + sr];
            float4 v = *(const float4*)(Kc + (size_t)(s0 + sr) * HH + r0 + rc4 * 4);
            v.x *= sc; v.y *= sc; v.z *= sc; v.w *= sc;
            *(float4*)&vT[sr][rc4 * 4] = v;
        }
        #pragma unroll
        for (int l = 0; l < 4; l++) {
            int f = tid + l * 256;
            int sr = f >> 5, cc = f & 31;
            float sc = Rc[s0 + sr];
            int gc = cc * 4 + ((cc >> 3) << 2);
            float4 v = *(const float4*)(Kc + (size_t)(s0 + sr) * HH + cc * 4);
            v.x *= sc; v.y *= sc; v.z *= sc; v.w *= sc;
            *(float4*)&aT[sr][gc] = v;
        }
        __syncthreads();
        #pragma unroll
        for (int ss = 0; ss < 32; ss++) {
            float2 vv = *(const float2*)&vT[ss][ty * 2];
            float4 a0 = *(const float4*)&aT[ss][gx];
            float4 a1 = *(const float4*)&aT[ss][gx + 4];
            float va[2] = {vv.x, vv.y};
            float aa[8] = {a0.x, a0.y, a0.z, a0.w, a1.x, a1.y, a1.z, a1.w};
            #pragma unroll
            for (int i = 0; i < 2; i++)
                #pragma unroll
                for (int j = 0; j < 8; j++)
                    acc[i][j] += va[i] * aa[j];
        }
        __syncthreads();
    }

    #pragma unroll
    for (int i = 0; i < 2; i++) {
        float* hp = H + ((size_t)bi * HH + r0 + ty * 2 + i) * HH + tx * 8;
        float4 o0 = {acc[i][0], acc[i][1], acc[i][2], acc[i][3]};
        float4 o1 = {acc[i][4], acc[i][5], acc[i][6], acc[i][7]};
        *(float4*)hp       = o0;
        *(float4*)(hp + 4) = o1;
    }
}

// ---------------------------------------------------------------------------
// B_start(c) = I + sum_{c'<c} H[c']. Exclusive prefix.
// ---------------------------------------------------------------------------
__global__ __launch_bounds__(256) void bprefix_kernel(
    const float* __restrict__ H, float* __restrict__ Bm)
{
    const int b   = blockIdx.x;
    const int idx = blockIdx.y * 256 + threadIdx.x;
    const int row = idx >> 7, col = idx & 127;
    float run = (row == col) ? 1.0f : 0.0f;
    for (int i = 0; i < NCH; i++) {
        size_t off = ((size_t)b * NCH + i) * HH * HH + idx;
        Bm[off] = run;
        run += H[off];
    }
}

// ---------------------------------------------------------------------------
// Invert 128x128 SPD B -> Ainv (static-indexed GJ, verified).
// ---------------------------------------------------------------------------
__global__ __launch_bounds__(256) void invert_kernel(
    const float* __restrict__ Bm, float* __restrict__ Ainv)
{
    const int bi  = blockIdx.x;
    const int tid = threadIdx.x;
    const int tr  = tid >> 4;      // row block 0..15
    const int tc  = tid & 15;      // col block 0..15
    const float* Bp = Bm  + (size_t)bi * HH * HH;
    float*       Ap = Ainv + (size_t)bi * HH * HH;

    __shared__ float rowk[HH];
    __shared__ float colk[HH];
    __shared__ float dsh;

    float M[8][8];
    #pragma unroll
    for (int ii = 0; ii < 8; ii++) {
        float4 a = *(const float4*)(Bp + (size_t)(tr*8+ii) * HH + tc*8);
        float4 b = *(const float4*)(Bp + (size_t)(tr*8+ii) * HH + tc*8 + 4);
        M[ii][0]=a.x; M[ii][1]=a.y; M[ii][2]=a.z; M[ii][3]=a.w;
        M[ii][4]=b.x; M[ii][5]=b.y; M[ii][6]=b.z; M[ii][7]=b.w;
    }

    for (int krb = 0; krb < 16; krb++) {
        const bool myrow = (tr == krb);
        const bool mycol = (tc == krb);
        #pragma unroll
        for (int kl = 0; kl < 8; kl++) {
            if (myrow && mycol) dsh = M[kl][kl];
            __syncthreads();
            const float ip = 1.0f / dsh;
            if (myrow) {
                #pragma unroll
                for (int jj = 0; jj < 8; jj++) {
                    float v = (mycol && jj == kl) ? ip : M[kl][jj] * ip;
                    M[kl][jj] = v;
                    rowk[tc*8 + jj] = v;
                }
            }
            if (mycol) {
                #pragma unroll
                for (int ii = 0; ii < 8; ii++)
                    colk[tr*8 + ii] = M[ii][kl];
            }
            __syncthreads();
            float rk[8];
            #pragma unroll
            for (int jj = 0; jj < 8; jj++) rk[jj] = rowk[tc*8 + jj];
            #pragma unroll
            for (int ii = 0; ii < 8; ii++) {
                const bool isk = myrow && (ii == kl);
                const float f = colk[tr*8 + ii];
                #pragma unroll
                for (int jj = 0; jj < 8; jj++) {
                    float upd = (mycol && jj == kl)
                              ? (-f * ip)
                              : fmaf(-f, rk[jj], M[ii][jj]);
                    M[ii][jj] = isk ? M[ii][jj] : upd;
                }
            }
            __syncthreads();
        }
    }

    #pragma unroll
    for (int ii = 0; ii < 8; ii++) {
        float4 a = {M[ii][0], M[ii][1], M[ii][2], M[ii][3]};
        float4 b = {M[ii][4], M[ii][5], M[ii][6], M[ii][7]};
        *(float4*)(Ap + (size_t)(tr*8+ii) * HH + tc*8)     = a;
        *(float4*)(Ap + (size_t)(tr*8+ii) * HH + tc*8 + 4) = b;
    }
}

// ---------------------------------------------------------------------------
// scan_kernel: 64 PARALLEL chunk-scans (v8 double-step body, verified).
// ---------------------------------------------------------------------------
__global__ __launch_bounds__(512, 1) void scan_kernel(
    const float* __restrict__ K, const float* __restrict__ rn,
    const float* __restrict__ Ainv, float* __restrict__ Z)
{
    __shared__ float Ybc[2][2][8 * 20];   // [buf][y1/y2], padded
    __shared__ float kst[2][2][8 * 20];   // [buf][k1/k2], padded

    const int bi  = blockIdx.x;          // b*NCH + c
    const int tid = threadIdx.x;
    const int r2  = tid >> 3;
    const int o8  = tid & 7;
    const int c0  = o8 * 16;
    const int r0  = 2 * r2, r1 = r0 + 1;

    const float* Kb   = K  + (size_t)bi * CC * HH;
    float*       Zb   = Z  + (size_t)bi * CC * HH;
    const float* rn_b = rn + (size_t)bi * CC;
    const float* Ap   = Ainv + (size_t)bi * HH * HH;

    f32x2 Ar0[8], Ar1[8];
    #pragma unroll
    for (int j = 0; j < 4; j++) {
        float4 a0 = *(const float4*)(Ap + (size_t)r0 * HH + c0 + 4 * j);
        float4 a1 = *(const float4*)(Ap + (size_t)r1 * HH + c0 + 4 * j);
        Ar0[2*j] = (f32x2){a0.x, a0.y}; Ar0[2*j+1] = (f32x2){a0.z, a0.w};
        Ar1[2*j] = (f32x2){a1.x, a1.y}; Ar1[2*j+1] = (f32x2){a1.z, a1.w};
    }

    const int woff = (r0 >> 4) * 20 + (r0 & 15);
    const int roff = o8 * 20;

    const bool ldr    = tid < 64;
    const int  whichk = tid >> 5;
    const int  l32    = tid & 31;
    const int  lpoff  = (l32 >> 2) * 20 + (l32 & 3) * 4;   // v8 8x20 mapping

    float4 pld = {0.f, 0.f, 0.f, 0.f};
    if (ldr) {
        float4 d0 = *(const float4*)(Kb + (size_t)whichk * HH + l32 * 4);
        *(float4*)&kst[0][whichk][lpoff] = d0;
        pld = *(const float4*)(Kb + (size_t)(2 + whichk) * HH + l32 * 4);
    }
    float2 rs_cur = ((const float2*)rn_b)[0];
    float2 rs_nxt = ((const float2*)rn_b)[1];
    __syncthreads();

    f32x2 k1[8], k2[8];
    #pragma unroll
    for (int j = 0; j < 4; j++) {
        float4 t1 = *(const float4*)&kst[0][0][roff + 4 * j];
        float4 t2 = *(const float4*)&kst[0][1][roff + 4 * j];
        k1[2*j] = (f32x2){t1.x, t1.y}; k1[2*j+1] = (f32x2){t1.z, t1.w};
        k2[2*j] = (f32x2){t2.x, t2.y}; k2[2*j+1] = (f32x2){t2.z, t2.w};
    }

    for (int i = 0; i < NIC; ++i) {
        const int yb = i & 1;
        const int nk = (i + 1) & 1;

        f32x2 y10 = {0,0}, y11 = {0,0}, y20 = {0,0}, y21 = {0,0};
        #pragma unroll
        for (int j = 0; j < 8; j++) {
            y10 += Ar0[j] * k1[j];
            y11 += Ar1[j] * k1[j];
            y20 += Ar0[j] * k2[j];
            y21 += Ar1[j] * k2[j];
        }
        float y1r0 = red8(y10.x + y10.y);
        float y1r1 = red8(y11.x + y11.y);
        float y2r0 = red8(y20.x + y20.y);
        float y2r1 = red8(y21.x + y21.y);
        if (o8 == 0) {
            *(float2*)&Ybc[yb][0][woff] = make_float2(y1r0, y1r1);
            *(float2*)&Ybc[yb][1][woff] = make_float2(y2r0, y2r1);
        }

        if (ldr && i + 1 < NIC) {
            *(float4*)&kst[nk][whichk][lpoff] = pld;
            if (i + 2 < NIC)
                pld = *(const float4*)(Kb + (size_t)(2*(i+2) + whichk) * HH + l32 * 4);
        }

        __syncthreads();

        f32x2 av1[8], av2[8];
        #pragma unroll
        for (int j = 0; j < 4; j++) {
            float4 t1 = *(const float4*)&Ybc[yb][0][roff + 4 * j];
            float4 t2 = *(const float4*)&Ybc[yb][1][roff + 4 * j];
            av1[2*j] = (f32x2){t1.x, t1.y}; av1[2*j+1] = (f32x2){t1.z, t1.w};
            av2[2*j] = (f32x2){t2.x, t2.y}; av2[2*j+1] = (f32x2){t2.z, t2.w};
        }

        f32x2 e11v = {0,0}, e21v = {0,0}, e22v = {0,0};
        #pragma unroll
        for (int j = 0; j < 8; j++) {
            e11v += av1[j] * k1[j];
            e21v += av1[j] * k2[j];
            e22v += av2[j] * k2[j];
        }
        float e11 = red8(e11v.x + e11v.y);
        float e21 = red8(e21v.x + e21v.y);
        float e22 = red8(e22v.x + e22v.y);

        #pragma unroll
        for (int j = 0; j < 4; j++) {
            float4 t1 = *(const float4*)&kst[nk][0][roff + 4 * j];
            float4 t2 = *(const float4*)&kst[nk][1][roff + 4 * j];
            k1[2*j] = (f32x2){t1.x, t1.y}; k1[2*j+1] = (f32x2){t1.z, t1.w};
            k2[2*j] = (f32x2){t2.x, t2.y}; k2[2*j+1] = (f32x2){t2.z, t2.w};
        }

        const float rn1 = rs_cur.x, rn2 = rs_cur.y;
        const float rn1sq = rn1 * rn1;
        const float rn2sq = rn2 * rn2;
        const float i1   = __builtin_amdgcn_rcpf(1.0f + rn1sq * e11);
        const float beta = rn1sq * e21 * i1;
        const float i2   = __builtin_amdgcn_rcpf(1.0f + rn2sq * (e22 - beta * e21));
        const float p2r0 = y2r0 - beta * y1r0;
        const float p2r1 = y2r1 - beta * y1r1;
        const float za1  = rn1 * i1;
        const float za2  = rn2 * i2;
        if (o8 == 0) {
            *(float2*)(Zb + (size_t)(2*i)     * HH + r0) =
                make_float2(za1 * y1r0, za1 * y1r1);
            *(float2*)(Zb + (size_t)(2*i + 1) * HH + r0) =
                make_float2(za2 * p2r0, za2 * p2r1);
        }

        const float cA1 = rn1sq * i1, cA2 = rn2sq * i2;
        const f32x2 u10 = {cA1 * y1r0, cA1 * y1r0};
        const f32x2 u11 = {cA1 * y1r1, cA1 * y1r1};
        const f32x2 u20 = {cA2 * p2r0, cA2 * p2r0};
        const f32x2 u21 = {cA2 * p2r1, cA2 * p2r1};
        const f32x2 bbv = {beta, beta};
        #pragma unroll
        for (int j = 0; j < 8; j++) {
            f32x2 pp = av2[j] - bbv * av1[j];
            Ar0[j] = Ar0[j] - u10 * av1[j] - u20 * pp;
            Ar1[j] = Ar1[j] - u11 * av1[j] - u21 * pp;
        }

        rs_cur = rs_nxt;
        if (i + 2 < NIC) rs_nxt = ((const float2*)rn_b)[i + 2];
    }
}

// ---------------------------------------------------------------------------
// Phase 2a: G[b][c] = V_chunk^T @ (diag(s) Z_chunk). Gapped aT.
// ---------------------------------------------------------------------------
__global__ __launch_bounds__(256) void gram_kernel(
    const float* __restrict__ V, const float* __restrict__ Z,
    const float* __restrict__ Sarr, float* __restrict__ G)
{
    const int bi = blockIdx.x;
    const int r0 = blockIdx.y * 32;

    const float* Vc = V + (size_t)bi * CC * HH;
    const float* Zc = Z + (size_t)bi * CC * HH;
    const float* Sc = Sarr + (size_t)bi * CC;

    __shared__ float vT[32][36];
    __shared__ float aT[32][WPAD];

    const int tid = threadIdx.x;
    const int tx = tid & 15, ty = tid >> 4;
    const int gx = tx * 8 + ((tx >> 2) << 2);

    float acc[2][8];
    #pragma unroll
    for (int i = 0; i < 2; i++)
        #pragma unroll
        for (int j = 0; j < 8; j++) acc[i][j] = 0.f;

    for (int s0 = 0; s0 < CC; s0 += 32) {
        {   int sr = tid >> 3, rc = tid & 7;
            float4 v = *(const float4*)(Vc + (size_t)(s0 + sr) * HH + r0 + rc * 4);
            *(float4*)&vT[sr][rc * 4] = v;
        }
        #pragma unroll
        for (int l = 0; l < 4; l++) {
            int f = tid + l * 256;
            int sr = f >> 5, cc = f & 31;
            float sv = Sc[s0 + sr];
            int gc = cc * 4 + ((cc >> 3) << 2);
            float4 v = *(const float4*)(Zc + (size_t)(s0 + sr) * HH + cc * 4);
            v.x *= sv; v.y *= sv; v.z *= sv; v.w *= sv;
            *(float4*)&aT[sr][gc] = v;
        }
        __syncthreads();
        #pragma unroll
        for (int ss = 0; ss < 32; ss++) {
            float2 vv = *(const float2*)&vT[ss][ty * 2];
            float4 a0 = *(const float4*)&aT[ss][gx];
            float4 a1 = *(const float4*)&aT[ss][gx + 4];
            float va[2] = {vv.x, vv.y};
            float aa[8] = {a0.x, a0.y, a0.z, a0.w, a1.x, a1.y, a1.z, a1.w};
            #pragma unroll
            for (int i = 0; i < 2; i++)
                #pragma unroll
                for (int j = 0; j < 8; j++)
                    acc[i][j] += va[i] * aa[j];
        }
        __syncthreads();
    }

    #pragma unroll
    for (int i = 0; i < 2; i++) {
        float* gp = G + ((size_t)bi * HH + r0 + ty * 2 + i) * HH + tx * 8;
        float4 o0 = {acc[i][0], acc[i][1], acc[i][2], acc[i][3]};
        float4 o1 = {acc[i][4], acc[i][5], acc[i][6], acc[i][7]};
        *(float4*)gp       = o0;
        *(float4*)(gp + 4) = o1;
    }
}

// ---------------------------------------------------------------------------
// Phase 2b: exclusive prefix Mpre.
// ---------------------------------------------------------------------------
__global__ __launch_bounds__(256) void prefix_kernel(
    const float* __restrict__ G, float* __restrict__ Mpre)
{
    const int b   = blockIdx.x;
    const int idx = blockIdx.y * 256 + threadIdx.x;
    float run = 0.f;
    for (int i = 0; i < NCH; i++) {
        size_t off = ((size_t)b * NCH + i) * HH * HH + idx;
        Mpre[off] = run;
        run += G[off];
    }
}

// ---------------------------------------------------------------------------
// Phase 2c: O = Q Mpre^T + tril(Q (sZ)^T) V. Grid (64,4). Gapped wT/S.
// ---------------------------------------------------------------------------
__global__ __launch_bounds__(256) void ochunk_kernel(
    const float* __restrict__ Q, const float* __restrict__ Z,
    const float* __restrict__ Sarr, const float* __restrict__ V,
    const float* __restrict__ Mpre, float* __restrict__ O)
{
    const int bi = blockIdx.x;
    const int t0 = blockIdx.y * 32;

    const float* Qc = Q    + (size_t)bi * CC * HH;
    const float* Zc = Z    + (size_t)bi * CC * HH;
    const float* Vc = V    + (size_t)bi * CC * HH;
    const float* Sc = Sarr + (size_t)bi * CC;
    const float* Mp = Mpre + (size_t)bi * HH * HH;
    float*       Oc = O    + (size_t)bi * CC * HH;

    __shared__ float S[32][WPAD];
    __shared__ float xT[32][36];
    __shared__ float wT[32][WPAD];

    const int tid = threadIdx.x;
    const int tx = tid & 15, ty = tid >> 4;
    const int gx = tx * 8 + ((tx >> 2) << 2);

    float acc[2][8];

    // ---- phase 1: S = tril(Q (sZ)^T)
    #pragma unroll
    for (int i = 0; i < 2; i++)
        #pragma unroll
        for (int j = 0; j < 8; j++) acc[i][j] = 0.f;
    for (int k0 = 0; k0 < HH; k0 += 32) {
        {   int r = tid >> 3, cg = tid & 7;
            float4 v = *(const float4*)(Qc + (size_t)(t0 + r) * HH + k0 + cg * 4);
            xT[cg*4+0][r] = v.x; xT[cg*4+1][r] = v.y;
            xT[cg*4+2][r] = v.z; xT[cg*4+3][r] = v.w;
        }
        #pragma unroll
        for (int l = 0; l < 4; l++) {
            int f = tid + l * 256;
            int sr = f >> 3, cg = f & 7;
            float sv = Sc[sr];
            int gc = gcol(sr);
            float4 v = *(const float4*)(Zc + (size_t)sr * HH + k0 + cg * 4);
            wT[cg*4+0][gc] = v.x * sv; wT[cg*4+1][gc] = v.y * sv;
            wT[cg*4+2][gc] = v.z * sv; wT[cg*4+3][gc] = v.w * sv;
        }
        __syncthreads();
        #pragma unroll
        for (int kk = 0; kk < 32; kk++) {
            float2 xv = *(const float2*)&xT[kk][ty * 2];
            float4 w0 = *(const float4*)&wT[kk][gx];
            float4 w1 = *(const float4*)&wT[kk][gx + 4];
            float xa[2] = {xv.x, xv.y};
            float wa[8] = {w0.x, w0.y, w0.z, w0.w, w1.x, w1.y, w1.z, w1.w};
            #pragma unroll
            for (int i = 0; i < 2; i++)
                #pragma unroll
                for (int j = 0; j < 8; j++)
                    acc[i][j] += xa[i] * wa[j];
        }
        __syncthreads();
    }
    #pragma unroll
    for (int i = 0; i < 2; i++) {
        int tl = t0 + ty * 2 + i;
        float m[8];
        #pragma unroll
        for (int j = 0; j < 8; j++)
            m[j] = (tx * 8 + j <= tl) ? acc[i][j] : 0.f;
        float4 o0 = {m[0], m[1], m[2], m[3]};
        float4 o1 = {m[4], m[5], m[6], m[7]};
        *(float4*)&S[ty*2+i][gx]     = o0;
        *(float4*)&S[ty*2+i][gx + 4] = o1;
    }

    // ---- phase 2: acc = Q @ Mpre^T
    #pragma unroll
    for (int i = 0; i < 2; i++)
        #pragma unroll
        for (int j = 0; j < 8; j++) acc[i][j] = 0.f;
    for (int k0 = 0; k0 < HH; k0 += 32) {
        {   int r = tid >> 3, cg = tid & 7;
            float4 v = *(const float4*)(Qc + (size_t)(t0 + r) * HH + k0 + cg * 4);
            xT[cg*4+0][r] = v.x; xT[cg*4+1][r] = v.y;
            xT[cg*4+2][r] = v.z; xT[cg*4+3][r] = v.w;
        }
        #pragma unroll
        for (int l = 0; l < 4; l++) {
            int f = tid + l * 256;
            int h = f >> 3, cg = f & 7;
            int gc = gcol(h);
            float4 v = *(const float4*)(Mp + (size_t)h * HH + k0 + cg * 4);
            wT[cg*4+0][gc] = v.x; wT[cg*4+1][gc] = v.y;
            wT[cg*4+2][gc] = v.z; wT[cg*4+3][gc] = v.w;
        }
        __syncthreads();
        #pragma unroll
        for (int kk = 0; kk < 32; kk++) {
            float2 xv = *(const float2*)&xT[kk][ty * 2];
            float4 w0 = *(const float4*)&wT[kk][gx];
            float4 w1 = *(const float4*)&wT[kk][gx + 4];
            float xa[2] = {xv.x, xv.y};
            float wa[8] = {w0.x, w0.y, w0.z, w0.w, w1.x, w1.y, w1.z, w1.w};
            #pragma unroll
            for (int i = 0; i < 2; i++)
                #pragma unroll
                for (int j = 0; j < 8; j++)
                    acc[i][j] += xa[i] * wa[j];
        }
        __syncthreads();
    }

    // ---- phase 3: acc += S @ V
    for (int s0 = 0; s0 < CC; s0 += 32) {
        #pragma unroll
        for (int l = 0; l < 4; l++) {
            int f = tid + l * 256;
            int sr = f >> 5, cc = f & 31;
            int gc = cc * 4 + ((cc >> 3) << 2);
            float4 v = *(const float4*)(Vc + (size_t)(s0 + sr) * HH + cc * 4);
            *(float4*)&wT[sr][gc] = v;
        }
        __syncthreads();
        #pragma unroll
        for (int ss = 0; ss < 32; ss++) {
            float4 w0 = *(const float4*)&wT[ss][gx];
            float4 w1 = *(const float4*)&wT[ss][gx + 4];
            float wa[8] = {w0.x, w0.y, w0.z, w0.w, w1.x, w1.y, w1.z, w1.w};
            int sgc = gcol(s0 + ss);
            float sv[2] = {S[ty*2][sgc], S[ty*2+1][sgc]};
            #pragma unroll
            for (int i = 0; i < 2; i++)
                #pragma unroll
                for (int j = 0; j < 8; j++)
                    acc[i][j] += sv[i] * wa[j];
        }
        __syncthreads();
    }

    #pragma unroll
    for (int i = 0; i < 2; i++) {
        float* op = Oc + (size_t)(t0 + ty * 2 + i) * HH + tx * 8;
        float4 o0 = {acc[i][0], acc[i][1], acc[i][2], acc[i][3]};
        float4 o1 = {acc[i][4], acc[i][5], acc[i][6], acc[i][7]};
        *(float4*)op       = o0;
        *(float4*)(op + 4) = o1;
    }
}

// ---------------------------------------------------------------------------
// Output v24: 128-row x 128-col tiles, acc2[8][4] packed (4 b128 per 64 FMA).
// Grid (BT/128, DD/128) = (64, 8) = 512 blocks = 2/CU balanced.
// oT[32][132] staging audited for 128 rows (writes r<=127, reads <=128).
// ---------------------------------------------------------------------------
__global__ __launch_bounds__(256) void out_kernel(
    const float* __restrict__ O, const float* __restrict__ Wo,
    const float* __restrict__ bo, float* __restrict__ out)
{
    const int row0 = blockIdx.x * 128;
    const int d0   = blockIdx.y * 128;

    __shared__ float oT[32][132];
    __shared__ float woT[32][WPAD];

    const int tid = threadIdx.x;
    const int tx = tid & 15;
    const int ty = tid >> 4;       // rows ty*8..+8
    const int gx = tx * 8 + ((tx >> 2) << 2);

    f32x2 acc2[8][4];
    #pragma unroll
    for (int i = 0; i < 8; i++)
        #pragma unroll
        for (int jp = 0; jp < 4; jp++) acc2[i][jp] = (f32x2){0.f, 0.f};

    for (int k0 = 0; k0 < HH; k0 += 32) {
        #pragma unroll
        for (int l = 0; l < 4; l++) {   // oT: 128 rows x 32 k (transposed)
            int f = tid + l * 256;
            int r = f >> 3;
            int cg = f & 7;
            float4 v = *(const float4*)(O + (size_t)(row0 + r) * HH + k0 + cg * 4);
            oT[cg*4+0][r] = v.x; oT[cg*4+1][r] = v.y;
            oT[cg*4+2][r] = v.z; oT[cg*4+3][r] = v.w;
        }
        #pragma unroll
        for (int l = 0; l < 4; l++) {   // woT: 128 d x 32 k (gapped)
            int f = tid + l * 256;
            int d = f >> 3;
            int cg = f & 7;
            int gc = gcol(d);
            float4 v = *(const float4*)(Wo + (size_t)(d0 + d) * HH + k0 + cg * 4);
            woT[cg*4+0][gc] = v.x; woT[cg*4+1][gc] = v.y;
            woT[cg*4+2][gc] = v.z; woT[cg*4+3][gc] = v.w;
        }
        __syncthreads();
        #pragma unroll
        for (int kk = 0; kk < 32; kk++) {
            float4 x0 = *(const float4*)&oT[kk][ty * 8];
            float4 x1 = *(const float4*)&oT[kk][ty * 8 + 4];
            float4 w0 = *(const float4*)&woT[kk][gx];
            float4 w1 = *(const float4*)&woT[kk][gx + 4];
            f32x2 wa[4] = {{w0.x, w0.y}, {w0.z, w0.w},
                           {w1.x, w1.y}, {w1.z, w1.w}};
            float xa[8] = {x0.x, x0.y, x0.z, x0.w, x1.x, x1.y, x1.z, x1.w};
            #pragma unroll
            for (int i = 0; i < 8; i++) {
                const f32x2 xb = {xa[i], xa[i]};
                #pragma unroll
                for (int jp = 0; jp < 4; jp++)
                    acc2[i][jp] += xb * wa[jp];
            }
        }
        __syncthreads();
    }

    #pragma unroll
    for (int i = 0; i < 8; i++) {
        int row = row0 + ty * 8 + i;
        float o[8] = {acc2[i][0].x, acc2[i][0].y, acc2[i][1].x, acc2[i][1].y,
                      acc2[i][2].x, acc2[i][2].y, acc2[i][3].x, acc2[i][3].y};
        #pragma unroll
        for (int j = 0; j < 8; j++) o[j] += bo[d0 + tx * 8 + j];
        float4 o0 = {o[0], o[1], o[2], o[3]};
        float4 o1 = {o[4], o[5], o[6], o[7]};
        *(float4*)(out + (size_t)row * DD + d0 + tx * 8)     = o0;
        *(float4*)(out + (size_t)row * DD + d0 + tx * 8 + 4) = o1;
    }
}

extern "C" void kernel_launch(void* const* d_in, const int* in_sizes, int n_in,
                              void* d_out, int out_size, void* d_ws, size_t ws_size,
                              hipStream_t stream) {
    const float* x  = (const float*)d_in[0];
    const float* Wq = (const float*)d_in[1];
    const float* bq = (const float*)d_in[2];
    const float* Wk = (const float*)d_in[3];
    const float* bk = (const float*)d_in[4];
    const float* Wv = (const float*)d_in[5];
    const float* bv = (const float*)d_in[6];
    const float* Wo = (const float*)d_in[7];
    const float* bo = (const float*)d_in[8];
    float* out = (float*)d_out;

    float* ws = (float*)d_ws;
    float* Q = ws;
    float* K = ws + (size_t)BT * HH;
    float* V = ws + (size_t)2 * BT * HH;
    float* O = ws + (size_t)3 * BT * HH;

    // d_out scratch (32 MB), float offsets (1<<20 floats = 4 MB each buf):
    //   Pp @0 (6 x 1M floats = 24 MB): proj3 -> combine, then DEAD.
    //   H @0, Bmat @1M, Ainv @2M, Z @3M, G @4M, Mpre @5M   (reuse Pp space)
    //   rn @6M floats (24 MB), Sarr just after.
    // All dead before out_kernel overwrites d_out.
    float* db   = (float*)d_out;
    float* Pp   = db;
    float* H    = db;
    float* Bmat = db + (size_t)1 * (1u << 20);
    float* Ainv = db + (size_t)2 * (1u << 20);
    float* Z    = db + (size_t)3 * (1u << 20);
    float* G    = db + (size_t)4 * (1u << 20);
    float* Mpre = db + (size_t)5 * (1u << 20);
    float* rn   = db + (size_t)6 * (1u << 20);
    float* Sarr = rn + BT;

    // 1. all three projections, k-split partials (384 blocks, 128-row tiles)
    dim3 pg(BT / 128, 6);
    proj3_kernel<<<pg, 256, 0, stream>>>(x, Wk, Wq, Wv, Pp);

    // 2. combine halves + bias; rn & s epilogues (memory-bound)
    combine_kernel<<<BT / 32, 256, 0, stream>>>(
        Pp, bk, bq, bv, K, Q, V, rn, Sarr);

    // 3. chunk-start inverse-Gram pipeline: H -> B_start -> A_start
    dim3 hg(NSCAN, 4);
    ugram_kernel<<<hg, 256, 0, stream>>>(K, rn, H);
    dim3 bp(BB, HH * HH / 256);
    bprefix_kernel<<<bp, 256, 0, stream>>>(H, Bmat);
    invert_kernel<<<NSCAN, 256, 0, stream>>>(Bmat, Ainv);

    // 4. 64 parallel chunk-scans
    scan_kernel<<<NSCAN, 512, 0, stream>>>(K, rn, Ainv, Z);

    // 5. phase-2 (alpha = s*z folded into staging) + output
    dim3 gg(NSCAN, 4);
    gram_kernel<<<gg, 256, 0, stream>>>(V, Z, Sarr, G);
    prefix_kernel<<<bp, 256, 0, stream>>>(G, Mpre);
    dim3 cg(NSCAN, 4);
    ochunk_kernel<<<cg, 256, 0, stream>>>(Q, Z, Sarr, V, Mpre, O);
    dim3 og(BT / 128, DD / 128);
    out_kernel<<<og, 256, 0, stream>>>(O, Wo, bo, out);
}